// Round 12
// baseline (111.431 us; speedup 1.0000x reference)
//
#include <hip/hip_runtime.h>
#include <hip/hip_fp16.h>

#define DIM   160
#define DIM2  25600
#define TY    16
#define TX    32
#define TZ    20
#define HY    22            // TY + 6
#define HX    38            // TX + 6
#define SS    51            // sIn row stride (bank-verified on HW, R7)
#define YSTR  39            // yc row stride (bank-verified on HW, R10)
#define NSL   26            // TZ + 6
#define NSITE (HY * HX)     // 836
#define NVOX_D 16384000.0

#define W0 0.03663285f
#define W1 0.11128076f
#define W2 0.21674532f
#define W3 0.27068213f

__global__ void ssim_zero_acc(double* acc) {
    if (threadIdx.x == 0 && blockIdx.x == 0) acc[0] = 0.0;
}

__global__ __launch_bounds__(256, 4) void ssim_main(const float* __restrict__ P,
                                                    const float* __restrict__ T,
                                                    double* __restrict__ acc) {
    const float Wf[7] = {W0, W1, W2, W3, W2, W1, W0};
    const __half2 wh[7] = {__float2half2_rn(W0), __float2half2_rn(W1),
                           __float2half2_rn(W2), __float2half2_rn(W3),
                           __float2half2_rn(W2), __float2half2_rn(W1),
                           __float2half2_rn(W0)};

    __shared__ __half2 sIn[HY * SS];     // (p,t) packed, stride 51 (4488 B)
    __shared__ __half2 ycMu[TY * YSTR];  // (yconv p, yconv t), stride 39
    __shared__ __half2 ycE2[TY * YSTR];  // (yconv p^2, yconv t^2)
    __shared__ float   ycPt[TY * YSTR];  // yconv p*t (f32)
    __shared__ float   red[4];

    const int tid = threadIdx.x;
    int bid = blockIdx.x;
    int b  = bid / 400;  int r  = bid - b * 400;   // 8 zc * 10 ty * 5 tx
    int zc = r / 50;     int r2 = r - zc * 50;
    int ty = r2 / 5;     int tx = r2 - ty * 5;

    const int base = b * (DIM * DIM * DIM);
    const int z0 = zc * TZ, y0 = ty * TY - 3, x0 = tx * TX - 3;

    // ---- hoisted staging sites (u = tid + 256k, k<4; 836 = 3*256 + 68) ----
    int gofs[4], lofs[4];
    bool ld[4], st[4];
#pragma unroll
    for (int k = 0; k < 4; ++k) {
        int u = tid + 256 * k;
        st[k] = (u < NSITE);
        int y = u / HX, x = u - y * HX;
        int gy = y0 + y, gx = x0 + x;
        ld[k] = st[k] & ((unsigned)gy < (unsigned)DIM) & ((unsigned)gx < (unsigned)DIM);
        gofs[k] = gy * DIM + gx;
        lofs[k] = y * SS + x;
    }

    // ---- y-conv pair-task bases: 304 tasks = 256 + 48 ----
    int ybR0, ybW0, ybR1, ybW1;
    {
        int t = tid;
        int yy = t / HX, x = t - yy * HX;
        ybR0 = (2 * yy) * SS + x;
        ybW0 = (2 * yy) * YSTR + x;
        int t1 = tid + 256; if (t1 > 303) t1 = 303;
        int yy1 = t1 / HX, x1 = t1 - yy1 * HX;
        ybR1 = (2 * yy1) * SS + x1;
        ybW1 = (2 * yy1) * YSTR + x1;
    }

    // ---- x-conv: row cy = tid>>4 (16 rows), pair xp = tid&15 -> 2 voxels ----
    const int xrd = (tid >> 4) * YSTR + 2 * (tid & 15);

    const __half2 hz = __float2half2_rn(0.f);
    __half2 azMu[2][7], azE2[2][7], azPt[7];
#pragma unroll
    for (int o = 0; o < 2; ++o)
#pragma unroll
        for (int j = 0; j < 7; ++j) { azMu[o][j] = hz; azE2[o][j] = hz; }
#pragma unroll
    for (int j = 0; j < 7; ++j) azPt[j] = hz;

    float lsum = 0.f;

    // y-conv vertical pair: 8 packed taps (stride 51) -> 2 rows x 3 arrays (stride 39)
    auto ytask = [&](int rb, int wb) {
        __half2 mu0 = hz, mu1 = hz, e20 = hz, e21 = hz;
        float pt0 = 0.f, pt1 = 0.f;
#pragma unroll
        for (int k = 0; k < 8; ++k) {
            __half2 v  = sIn[rb + k * SS];
            __half2 v2 = __hmul2(v, v);
            __half2 vs = __halves2half2(__high2half(v), __low2half(v));
            float ptf  = __low2float(__hmul2(v, vs));
            if (k < 7) {
                mu0 = __hfma2(wh[k], v, mu0);
                e20 = __hfma2(wh[k], v2, e20);
                pt0 = fmaf(Wf[k], ptf, pt0);
            }
            if (k >= 1) {
                mu1 = __hfma2(wh[k - 1], v, mu1);
                e21 = __hfma2(wh[k - 1], v2, e21);
                pt1 = fmaf(Wf[k - 1], ptf, pt1);
            }
        }
        ycMu[wb] = mu0; ycMu[wb + YSTR] = mu1;
        ycE2[wb] = e20; ycE2[wb + YSTR] = e21;
        ycPt[wb] = pt0; ycPt[wb + YSTR] = pt1;
    };

    // ---- prologue: stage slice zs = z0-3 ----
    {
        int zs = z0 - 3;
        bool zok = (unsigned)zs < (unsigned)DIM;
        const float* Pp = P + base + zs * DIM2;
        const float* Tp = T + base + zs * DIM2;
        float rp[4], rt[4];
#pragma unroll
        for (int k = 0; k < 4; ++k) {
            rp[k] = 0.f; rt[k] = 0.f;
            if (zok && ld[k]) { rp[k] = Pp[gofs[k]]; rt[k] = Tp[gofs[k]]; }
        }
#pragma unroll
        for (int k = 0; k < 4; ++k)
            if (st[k]) sIn[lofs[k]] = __floats2half2_rn(rp[k], rt[k]);
    }
    __syncthreads();

    for (int i = 0; i < NSL; ++i) {
        const bool hn = (i + 1 < NSL);
        float rp[4], rt[4];

        // ---- prefetch next slice into regs (hides HBM under y-conv) ----
        if (hn) {
            int zs = z0 + i - 2;
            bool zok = (unsigned)zs < (unsigned)DIM;
            const float* Pp = P + base + zs * DIM2;
            const float* Tp = T + base + zs * DIM2;
#pragma unroll
            for (int k = 0; k < 4; ++k) {
                rp[k] = 0.f; rt[k] = 0.f;
                if (zok && ld[k]) { rp[k] = Pp[gofs[k]]; rt[k] = Tp[gofs[k]]; }
            }
        }

        // ---- phase A: y-conv (304 pair tasks on 256 threads) ----
        ytask(ybR0, ybW0);
        if (tid < 48) ytask(ybR1, ybW1);
        __syncthreads();

        // ---- phase B: x-conv (2 outputs/thread, all b32 reads) ----
        __half2 muw[8], e2w[8]; float ptw[8];
#pragma unroll
        for (int m = 0; m < 8; ++m) {
            muw[m] = ycMu[xrd + m];
            e2w[m] = ycE2[xrd + m];
            ptw[m] = ycPt[xrd + m];
        }
        __half2 xmu[2], xe2[2]; float xpt[2];
#pragma unroll
        for (int o = 0; o < 2; ++o) {
            __half2 am = hz, ae = hz; float ap = 0.f;
#pragma unroll
            for (int k = 0; k < 7; ++k) {
                am = __hfma2(wh[k], muw[o + k], am);
                ae = __hfma2(wh[k], e2w[o + k], ae);
                ap = fmaf(Wf[k], ptw[o + k], ap);
            }
            xmu[o] = am; xe2[o] = ae; xpt[o] = ap;
        }

        // ---- z scatter ----
        __half2 ptp = __floats2half2_rn(xpt[0], xpt[1]);
#pragma unroll
        for (int j = 0; j < 7; ++j) {
            __half2 w2 = wh[6 - j];
            azMu[0][j] = __hfma2(w2, xmu[0], azMu[0][j]);
            azMu[1][j] = __hfma2(w2, xmu[1], azMu[1][j]);
            azE2[0][j] = __hfma2(w2, xe2[0], azE2[0][j]);
            azE2[1][j] = __hfma2(w2, xe2[1], azE2[1][j]);
            azPt[j]    = __hfma2(w2, ptp,    azPt[j]);
        }

        // ---- SSIM on completed slot 0 (2 voxels) ----
        if (i >= 6) {
            float eptv[2] = {__low2float(azPt[0]), __high2float(azPt[0])};
#pragma unroll
            for (int o = 0; o < 2; ++o) {
                float mp = __low2float(azMu[o][0]), mt = __high2float(azMu[o][0]);
                float ep2 = __low2float(azE2[o][0]), et2 = __high2float(azE2[o][0]);
                float mp2 = mp * mp, mt2 = mt * mt, mpt = mp * mt;
                float num = fmaf(2.f, mpt, 1e-4f) * fmaf(2.f, eptv[o] - mpt, 9e-4f);
                float den = (mp2 + mt2 + 1e-4f) * ((ep2 - mp2) + (et2 - mt2) + 9e-4f);
                lsum += num * __builtin_amdgcn_rcpf(den);
            }
        }

        // ---- shift z pipes ----
#pragma unroll
        for (int j = 0; j < 6; ++j) {
            azMu[0][j] = azMu[0][j + 1];
            azMu[1][j] = azMu[1][j + 1];
            azE2[0][j] = azE2[0][j + 1];
            azE2[1][j] = azE2[1][j + 1];
            azPt[j]    = azPt[j + 1];
        }
        azMu[0][6] = hz; azMu[1][6] = hz;
        azE2[0][6] = hz; azE2[1][6] = hz;
        azPt[6] = hz;

        // ---- commit next slice (b32 packed writes) ----
        if (hn) {
#pragma unroll
            for (int k = 0; k < 4; ++k)
                if (st[k]) sIn[lofs[k]] = __floats2half2_rn(rp[k], rt[k]);
        }
        __syncthreads();
    }

    // ---- block reduction, one f64 atomic ----
#pragma unroll
    for (int off = 32; off > 0; off >>= 1) lsum += __shfl_down(lsum, off);
    if ((tid & 63) == 0) red[tid >> 6] = lsum;
    __syncthreads();
    if (tid == 0) atomicAdd(acc, (double)(red[0] + red[1] + red[2] + red[3]));
}

__global__ void ssim_finalize(const double* __restrict__ acc, float* __restrict__ out) {
    if (threadIdx.x == 0 && blockIdx.x == 0)
        out[0] = 1.f - (float)(acc[0] / NVOX_D);
}

extern "C" void kernel_launch(void* const* d_in, const int* in_sizes, int n_in,
                              void* d_out, int out_size, void* d_ws, size_t ws_size,
                              hipStream_t stream) {
    const float* P = (const float*)d_in[0];
    const float* T = (const float*)d_in[1];
    float* out = (float*)d_out;
    double* acc = (double*)d_ws;

    ssim_zero_acc<<<1, 64, 0, stream>>>(acc);
    ssim_main<<<4 * 8 * 10 * 5, 256, 0, stream>>>(P, T, acc);
    ssim_finalize<<<1, 64, 0, stream>>>(acc, out);
}